// Round 6
// baseline (3058.218 us; speedup 1.0000x reference)
//
#include <hip/hip_runtime.h>
#include <math.h>

#define BB 128
#define NN 2048
#define CMID 64
#define HH 128
#define NCLS 40
#define CHUNK 128
#define EPSV 1e-5f

__device__ __forceinline__ float fsigmoid(float x) {
    return 1.0f / (1.0f + __expf(-x));
}
__device__ __forceinline__ float ftanh2(float x) {
    return 2.0f / (1.0f + __expf(-2.0f * x)) - 1.0f;
}
__device__ __forceinline__ void fma4(float& a, const float4 w, const float4 v) {
    a = fmaf(w.x, v.x, a);
    a = fmaf(w.y, v.y, a);
    a = fmaf(w.z, v.z, a);
    a = fmaf(w.w, v.w, a);
}
// asm-pinned loads: results cannot be rematerialized -> weights stay resident
__device__ __forceinline__ float4 pin_load4(const float* p) {
    float4 r;
    asm volatile("global_load_dwordx4 %0, %1, off\n\ts_waitcnt vmcnt(0)"
                 : "=v"(r) : "v"(p) : "memory");
    return r;
}
__device__ __forceinline__ float pin_load1(const float* p) {
    float r;
    asm volatile("global_load_dword %0, %1, off\n\ts_waitcnt vmcnt(0)"
                 : "=v"(r) : "v"(p) : "memory");
    return r;
}

// 512 threads: thread = (group g = t>>3, slice s = t&7).
// Thread owns 8 gate rows (units {g, g+64} x 4 gates) over a 24-dim slice
// (hc dims [s*8,s*8+8), h dims [s*16,s*16+16)): 192 weight floats, pinned.
// Each operand float feeds 8 FMAs -> LDS traffic 49KB/step/CU (~576cyc) under
// the 768cyc FMA floor.  One barrier per step; bias added AFTER the reduce.
__global__ __attribute__((amdgpu_flat_work_group_size(512, 512),
                          amdgpu_waves_per_eu(2, 2)))
void lstm_seq_kernel(const float* __restrict__ x,
                     const float* __restrict__ conv_w, const float* __restrict__ conv_b,
                     const float* __restrict__ gamma,  const float* __restrict__ beta,
                     const float* __restrict__ rmean,  const float* __restrict__ rvar,
                     const float* __restrict__ W_ih,   const float* __restrict__ W_hh,
                     const float* __restrict__ b_ih,   const float* __restrict__ b_hh,
                     const float* __restrict__ W_out,  const float* __restrict__ b_out,
                     float* __restrict__ out)
{
    __shared__ float hc_s[CHUNK * CMID];     // 32 KB, unpadded (2-way = free)
    __shared__ float h_p[2][8][20];          // padded: slice bases at 8 distinct bank-quads
    __shared__ float cA0[CMID], cA1[CMID], cA2[CMID], cD[CMID];

    const int t = threadIdx.x;
    const int b = blockIdx.x;
    const int g = t >> 3;    // row-group 0..63 -> units {g, g+64}
    const int s = t & 7;     // slice 0..7

    if (t < CMID) {
        float inv = gamma[t] * rsqrtf(rvar[t] + EPSV);
        cA0[t] = conv_w[t * 3 + 0] * inv;
        cA1[t] = conv_w[t * 3 + 1] * inv;
        cA2[t] = conv_w[t * 3 + 2] * inv;
        cD[t]  = (conv_b[t] - rmean[t]) * inv + beta[t];
    }
    if (t < 2 * 8 * 20) ((float*)h_p)[t] = 0.0f;

    // ---- pinned per-thread weights: 48 float4 = 192 VGPRs + 8 biases ----
    float4 wih[4][2][2];   // [gate][unit][2]  : 8 ih dims per row
    float4 whh[4][2][4];   // [gate][unit][4]  : 16 hh dims per row
    float  bias[4][2];
    #pragma unroll
    for (int q = 0; q < 4; ++q) {
        #pragma unroll
        for (int u = 0; u < 2; ++u) {
            const int r = q * HH + g + u * 64;
            const float* pih = W_ih + (size_t)r * CMID + s * 8;
            wih[q][u][0] = pin_load4(pih);
            wih[q][u][1] = pin_load4(pih + 4);
            const float* phh = W_hh + (size_t)r * HH + s * 16;
            #pragma unroll
            for (int i = 0; i < 4; ++i) whh[q][u][i] = pin_load4(phh + 4 * i);
            bias[q][u] = pin_load1(b_ih + r) + pin_load1(b_hh + r);
        }
    }

    float c0 = 0.0f, c1 = 0.0f;
    const float* xb = x + (size_t)b * NN * 3;

    for (int ch = 0; ch < NN / CHUNK; ++ch) {
        const int base = ch * CHUNK;
        __syncthreads();   // prior chunk fully consumed; init writes visible

        // ---- precompute fp32 hc for this chunk ----
        #pragma unroll
        for (int i = 0; i < (CHUNK * CMID) / 512; ++i) {   // 16 iters
            int v  = i * 512 + t;
            int n  = v >> 6;          // wave-uniform
            int cc = v & 63;
            float x0 = xb[(base + n) * 3 + 0];
            float x1 = xb[(base + n) * 3 + 1];
            float x2 = xb[(base + n) * 3 + 2];
            float hcv = fmaxf(cD[cc] + cA0[cc] * x0 + cA1[cc] * x1 + cA2[cc] * x2, 0.0f);
            hc_s[n * CMID + cc] = hcv;
        }
        __syncthreads();

        // ---- recurrence: one barrier per step ----
        #pragma unroll 2
        for (int k = 0; k < CHUNK; ++k) {
            const int p = k & 1;    // base is even -> global parity = k&1
            float a[4][2] = {{0.f, 0.f}, {0.f, 0.f}, {0.f, 0.f}, {0.f, 0.f}};

            const float4* hcp = (const float4*)&hc_s[k * CMID + s * 8];  // 2 x 16B
            const float4* hp  = (const float4*)&h_p[p][s][0];            // 4 x 16B

            float4 v0 = hcp[0], v1 = hcp[1];
            #pragma unroll
            for (int q = 0; q < 4; ++q) {
                fma4(a[q][0], wih[q][0][0], v0); fma4(a[q][1], wih[q][1][0], v0);
                fma4(a[q][0], wih[q][0][1], v1); fma4(a[q][1], wih[q][1][1], v1);
            }
            #pragma unroll
            for (int i = 0; i < 4; ++i) {
                float4 uv = hp[i];
                #pragma unroll
                for (int q = 0; q < 4; ++q) {
                    fma4(a[q][0], whh[q][0][i], uv);
                    fma4(a[q][1], whh[q][1][i], uv);
                }
            }

            // reduce across the 8 slice-lanes (masks 1,2,4 stay in-group)
            #pragma unroll
            for (int m = 1; m <= 4; m <<= 1) {
                #pragma unroll
                for (int q = 0; q < 4; ++q) {
                    a[q][0] += __shfl_xor(a[q][0], m);
                    a[q][1] += __shfl_xor(a[q][1], m);
                }
            }

            // bias AFTER the reduce
            float gi0 = fsigmoid(a[0][0] + bias[0][0]);
            float gf0 = fsigmoid(a[1][0] + bias[1][0]);
            float gg0 = ftanh2 (a[2][0] + bias[2][0]);
            float go0 = fsigmoid(a[3][0] + bias[3][0]);
            float gi1 = fsigmoid(a[0][1] + bias[0][1]);
            float gf1 = fsigmoid(a[1][1] + bias[1][1]);
            float gg1 = ftanh2 (a[2][1] + bias[2][1]);
            float go1 = fsigmoid(a[3][1] + bias[3][1]);

            c0 = gf0 * c0 + gi0 * gg0;           // identical in all 8 replicas
            c1 = gf1 * c1 + gi1 * gg1;
            float hv0 = go0 * ftanh2(c0);
            float hv1 = go1 * ftanh2(c1);

            if (s == 0) {
                const int j1 = g + 64;
                h_p[p ^ 1][g >> 4][g & 15]   = hv0;
                h_p[p ^ 1][j1 >> 4][j1 & 15] = hv1;
            }
            __syncthreads();
        }
    }

    // ---- classifier head: final h is in parity-0 buffer (last step k=127 -> writes p^1=0) ----
    if (t < NCLS) {
        float acc = b_out[t];
        const float* wr = W_out + (size_t)t * HH;
        #pragma unroll
        for (int jj = 0; jj < HH; ++jj)
            acc = fmaf(wr[jj], h_p[0][jj >> 4][jj & 15], acc);
        out[(size_t)b * NCLS + t] = acc;
    }
}

extern "C" void kernel_launch(void* const* d_in, const int* in_sizes, int n_in,
                              void* d_out, int out_size, void* d_ws, size_t ws_size,
                              hipStream_t stream) {
    const float* x      = (const float*)d_in[0];
    const float* conv_w = (const float*)d_in[1];
    const float* conv_b = (const float*)d_in[2];
    const float* gamma  = (const float*)d_in[3];
    const float* beta   = (const float*)d_in[4];
    const float* rmean  = (const float*)d_in[5];
    const float* rvar   = (const float*)d_in[6];
    const float* W_ih   = (const float*)d_in[7];
    const float* W_hh   = (const float*)d_in[8];
    const float* b_ih   = (const float*)d_in[9];
    const float* b_hh   = (const float*)d_in[10];
    const float* W_out  = (const float*)d_in[11];
    const float* b_out  = (const float*)d_in[12];
    float* out = (float*)d_out;

    lstm_seq_kernel<<<BB, 512, 0, stream>>>(x, conv_w, conv_b, gamma, beta,
                                            rmean, rvar, W_ih, W_hh, b_ih, b_hh,
                                            W_out, b_out, out);
}

// Round 7
// 2137.127 us; speedup vs baseline: 1.4310x; 1.4310x over previous
//
#include <hip/hip_runtime.h>
#include <math.h>

#define BB 128
#define NN 2048
#define CMID 64
#define HH 128
#define G4 512
#define NCLS 40
#define CH 64            // timesteps per chunk
#define NCH (NN / CH)
#define EPSV 1e-5f

__device__ __forceinline__ float fsigmoid(float x) {
    return 1.0f / (1.0f + __expf(-x));
}
__device__ __forceinline__ float ftanh2(float x) {
    return 2.0f / (1.0f + __expf(-2.0f * x)) - 1.0f;
}
__device__ __forceinline__ void fma4(float& a, const float4 w, const float4 v) {
    a = fmaf(w.x, v.x, a);
    a = fmaf(w.y, v.y, a);
    a = fmaf(w.z, v.z, a);
    a = fmaf(w.w, v.w, a);
}

// 512 threads: thread = (unit j = t>>2, slice s = t&3).
// Persistent registers: W_hh rows {q*128+j} over h-dims [s*32, s*32+32):
// 32 float4 = 128 VGPRs.  __launch_bounds__(512,1) -> 256-VGPR cap
// (allocator observed to target 2x the declared min waves: 2->128, 4->64).
// Per chunk: phase-0 conv+BN+ReLU -> hcT[LDS]; phase-1 xg = bias + W_ih*hc
// (W_ih streamed from L1/L2, 2KB/step amortized) -> xg_s[LDS]; phase-2 the
// serial recurrence reads only xg_s + h (LDS) + whh (regs), 1 barrier/step.
__global__ __launch_bounds__(512, 1)
void lstm_seq_kernel(const float* __restrict__ x,
                     const float* __restrict__ conv_w, const float* __restrict__ conv_b,
                     const float* __restrict__ gamma,  const float* __restrict__ beta,
                     const float* __restrict__ rmean,  const float* __restrict__ rvar,
                     const float* __restrict__ W_ih,   const float* __restrict__ W_hh,
                     const float* __restrict__ b_ih,   const float* __restrict__ b_hh,
                     const float* __restrict__ W_out,  const float* __restrict__ b_out,
                     float* __restrict__ out)
{
    __shared__ float xg_s[CH][G4];      // 128 KB: input-side gate pre-activations
    __shared__ float hcT[CMID][CH];     // 16 KB:  hc transposed [channel][time]
    __shared__ float h_p[2][4][36];     // padded h slices (s*36: banks 0/4/8/12)
    __shared__ float bias_s[G4];        // b_ih + b_hh
    __shared__ float cf[4][CMID];       // folded conv+BN coeffs

    const int t = threadIdx.x;
    const int b = blockIdx.x;
    const int j = t >> 2;    // unit 0..127
    const int s = t & 3;     // h-slice 0..3 (32 dims each)

    if (t < CMID) {
        float inv = gamma[t] * rsqrtf(rvar[t] + EPSV);
        cf[0][t] = conv_w[t * 3 + 0] * inv;
        cf[1][t] = conv_w[t * 3 + 1] * inv;
        cf[2][t] = conv_w[t * 3 + 2] * inv;
        cf[3][t] = (conv_b[t] - rmean[t]) * inv + beta[t];
    }
    bias_s[t] = b_ih[t] + b_hh[t];
    if (t < 2 * 4 * 36) ((float*)h_p)[t] = 0.0f;

    // ---- persistent W_hh slices: 4 gate rows x 32 dims = 128 VGPRs ----
    float4 whh[4][8];
    #pragma unroll
    for (int q = 0; q < 4; ++q) {
        const float* p = W_hh + (size_t)(q * HH + j) * HH + s * 32;
        #pragma unroll
        for (int i = 0; i < 8; ++i) whh[q][i] = *(const float4*)(p + 4 * i);
    }

    float c_reg = 0.0f;
    const float* xb = x + (size_t)b * NN * 3;

    for (int ch = 0; ch < NCH; ++ch) {
        const int base = ch * CH;
        __syncthreads();   // prior chunk fully consumed; init writes visible

        // ---- phase-0: conv+BN+ReLU -> hcT[c][n] (transposed) ----
        {
            const int n = t & 63;
            const int c0 = t >> 6;   // 0..7
            float x0 = xb[(base + n) * 3 + 0];
            float x1 = xb[(base + n) * 3 + 1];
            float x2 = xb[(base + n) * 3 + 2];
            #pragma unroll
            for (int i = 0; i < 8; ++i) {
                int c = i * 8 + c0;
                float hv = cf[3][c] + cf[0][c] * x0 + cf[1][c] * x1 + cf[2][c] * x2;
                hcT[c][n] = fmaxf(hv, 0.0f);
            }
        }
        __syncthreads();

        // ---- phase-1: xg_s[n][r] = bias[r] + sum_c W_ih[r,c]*hc[n,c] ----
        // thread covers rows {q*128+j} (2 passes x 2 rows) x timesteps [s*16, s*16+16)
        for (int pass = 0; pass < 2; ++pass) {
            const int r0 = (pass * 2 + 0) * HH + j;
            const int r1 = (pass * 2 + 1) * HH + j;
            float acc0[16], acc1[16];
            const float b0 = bias_s[r0], b1 = bias_s[r1];
            #pragma unroll
            for (int n = 0; n < 16; ++n) { acc0[n] = b0; acc1[n] = b1; }
            const float* w0p = W_ih + (size_t)r0 * CMID;
            const float* w1p = W_ih + (size_t)r1 * CMID;
            for (int k4 = 0; k4 < 16; ++k4) {
                float4 w0 = *(const float4*)(w0p + k4 * 4);
                float4 w1 = *(const float4*)(w1p + k4 * 4);
                const float* w0f = (const float*)&w0;
                const float* w1f = (const float*)&w1;
                #pragma unroll
                for (int kk = 0; kk < 4; ++kk) {
                    const int k = k4 * 4 + kk;
                    const float wa = w0f[kk];
                    const float wb = w1f[kk];
                    const float4* hc4 = (const float4*)&hcT[k][s * 16];
                    #pragma unroll
                    for (int i2 = 0; i2 < 4; ++i2) {
                        float4 hv = hc4[i2];
                        acc0[i2 * 4 + 0] = fmaf(wa, hv.x, acc0[i2 * 4 + 0]);
                        acc0[i2 * 4 + 1] = fmaf(wa, hv.y, acc0[i2 * 4 + 1]);
                        acc0[i2 * 4 + 2] = fmaf(wa, hv.z, acc0[i2 * 4 + 2]);
                        acc0[i2 * 4 + 3] = fmaf(wa, hv.w, acc0[i2 * 4 + 3]);
                        acc1[i2 * 4 + 0] = fmaf(wb, hv.x, acc1[i2 * 4 + 0]);
                        acc1[i2 * 4 + 1] = fmaf(wb, hv.y, acc1[i2 * 4 + 1]);
                        acc1[i2 * 4 + 2] = fmaf(wb, hv.z, acc1[i2 * 4 + 2]);
                        acc1[i2 * 4 + 3] = fmaf(wb, hv.w, acc1[i2 * 4 + 3]);
                    }
                }
            }
            #pragma unroll
            for (int n = 0; n < 16; ++n) {
                xg_s[s * 16 + n][r0] = acc0[n];
                xg_s[s * 16 + n][r1] = acc1[n];
            }
        }
        __syncthreads();

        // ---- phase-2: serial recurrence, one barrier per step ----
        for (int k = 0; k < CH; ++k) {
            const int p = (base + k) & 1;
            float a0, a1, a2, a3;
            if (s == 0) {
                a0 = xg_s[k][0 * HH + j];
                a1 = xg_s[k][1 * HH + j];
                a2 = xg_s[k][2 * HH + j];
                a3 = xg_s[k][3 * HH + j];
            } else {
                a0 = a1 = a2 = a3 = 0.0f;
            }
            const float4* hp = (const float4*)&h_p[p][s][0];
            #pragma unroll
            for (int i = 0; i < 8; ++i) {
                float4 hv = hp[i];
                fma4(a0, whh[0][i], hv);
                fma4(a1, whh[1][i], hv);
                fma4(a2, whh[2][i], hv);
                fma4(a3, whh[3][i], hv);
            }
            // reduce across the 4 slice-lanes (masks 1,2 -> quad-perm)
            a0 += __shfl_xor(a0, 1); a0 += __shfl_xor(a0, 2);
            a1 += __shfl_xor(a1, 1); a1 += __shfl_xor(a1, 2);
            a2 += __shfl_xor(a2, 1); a2 += __shfl_xor(a2, 2);
            a3 += __shfl_xor(a3, 1); a3 += __shfl_xor(a3, 2);

            float gi = fsigmoid(a0);
            float gf = fsigmoid(a1);
            float gg = ftanh2(a2);
            float go = fsigmoid(a3);
            c_reg = gf * c_reg + gi * gg;           // identical in all 4 replicas
            float hv = go * ftanh2(c_reg);

            if (s == 0) h_p[p ^ 1][j >> 5][j & 31] = hv;
            __syncthreads();
        }
    }

    // ---- classifier head: final h in parity-0 buffer ----
    if (t < NCLS) {
        float acc = b_out[t];
        const float* wr = W_out + (size_t)t * HH;
        #pragma unroll
        for (int jj = 0; jj < HH; ++jj)
            acc = fmaf(wr[jj], h_p[0][jj >> 5][jj & 31], acc);
        out[(size_t)b * NCLS + t] = acc;
    }
}

extern "C" void kernel_launch(void* const* d_in, const int* in_sizes, int n_in,
                              void* d_out, int out_size, void* d_ws, size_t ws_size,
                              hipStream_t stream) {
    const float* x      = (const float*)d_in[0];
    const float* conv_w = (const float*)d_in[1];
    const float* conv_b = (const float*)d_in[2];
    const float* gamma  = (const float*)d_in[3];
    const float* beta   = (const float*)d_in[4];
    const float* rmean  = (const float*)d_in[5];
    const float* rvar   = (const float*)d_in[6];
    const float* W_ih   = (const float*)d_in[7];
    const float* W_hh   = (const float*)d_in[8];
    const float* b_ih   = (const float*)d_in[9];
    const float* b_hh   = (const float*)d_in[10];
    const float* W_out  = (const float*)d_in[11];
    const float* b_out  = (const float*)d_in[12];
    float* out = (float*)d_out;
    (void)d_ws; (void)ws_size; (void)in_sizes; (void)n_in; (void)out_size;

    lstm_seq_kernel<<<BB, 512, 0, stream>>>(x, conv_w, conv_b, gamma, beta,
                                            rmean, rvar, W_ih, W_hh, b_ih, b_hh,
                                            W_out, b_out, out);
}